// Round 1
// baseline (108.519 us; speedup 1.0000x reference)
//
#include <hip/hip_runtime.h>

#define BLK 512
#define MT 32            // mfma tile edge
#define IA 2             // A-frags per wave
#define IB 512           // rows per block = 8 waves * 32 * IA
#define TJQ 512          // q points per LDS chunk
#define SJ 4             // j-slices per (dir,b) -> 512 blocks, one dispatch round

typedef __attribute__((ext_vector_type(8))) short short8;
typedef __attribute__((ext_vector_type(16))) float f32x16;

__device__ __forceinline__ unsigned int fmap(float f) {
  unsigned int b = __float_as_uint(f);
  return (b & 0x80000000u) ? ~b : (b | 0x80000000u);
}
__device__ __forceinline__ float funmap(unsigned int u) {
  return __uint_as_float((u & 0x80000000u) ? (u ^ 0x80000000u) : ~u);
}
__device__ __forceinline__ unsigned short f2bf(float f) {
  unsigned int u = __float_as_uint(f);
  u += 0x7FFFu + ((u >> 16) & 1u);
  return (unsigned short)(u >> 16);
}
__device__ __forceinline__ float bf2f(unsigned short h) {
  return __uint_as_float(((unsigned int)h) << 16);
}
__device__ __forceinline__ unsigned int pk(unsigned short a, unsigned short b) {
  return (unsigned int)a | ((unsigned int)b << 16);
}

union FragU { uint4 u; short8 s; };

// R13: single-MFMA step, no s_nops. Hazard coverage comes from the software
// pipeline: between an MF writing dX and the first v_min reading dX there are
// always >= 1 MIN16 block (32 cyc) + 1 MF (8 cyc) of OTHER work — margin 40
// vs the 18-cycle D-write->VALU-read minimum validated in R11.
#define MF(d, a, b)                                                   \
  asm("v_mfma_f32_32x32x16_bf16 %0, %1, %2, %3"                       \
      : "=&v"(d) : "v"(a), "v"(b), "v"(zc))

// 16x v_min_f32 (2-op). Doubles min-VALU vs min3 pairing but keeps only two
// 16-reg d-tiles live (32 VGPRs), which is what lets the whole pinned set
// (run 32 + d 32 + zc 16 + af 8 + b 16) fit the 128-reg/wave budget at
// 4 waves/SIMD with zero AGPR shuttling.
#define MIN16(acc, d)                                                 \
  do {                                                                \
    _Pragma("unroll")                                                 \
    for (int r_ = 0; r_ < 16; ++r_)                                   \
      asm("v_min_f32 %0, %0, %1" : "+v"(acc[r_]) : "v"(d[r_]));       \
  } while (0)

// Fence: nothing may cross. Pins each MIN16 block into the slot AFTER the MF
// that covers its hazard window (compiler would otherwise hoist the
// independent v_mins right up against their producing MFMA).
#define SB0 __builtin_amdgcn_sched_barrier(0)

// D_ij = |q_j|^2 - 2 p_i.q_j via split-bf16-compensated MFMA (k-slot layout
// verified R5-R11, absmax margin 0). R13: 2-deep tile pipeline (MF(k) ||
// min(k-1)), raw s_barrier (q-prefetch stays in flight, no vmcnt drain),
// B-fragment prefetch one pair ahead.
__global__ __launch_bounds__(BLK, 4) void cl_mfma(
    const float* __restrict__ A, const float* __restrict__ Bp,
    unsigned int* __restrict__ umin, int N, int jslice, int Bn) {
  __shared__ uint4 sA[2][IB];   // A-vec halves [g][row]
  __shared__ uint4 sB[2][TJQ];  // B-vec halves [g][point]
  __shared__ float sNP[IB];     // |p|^2 per row

  const int zi = blockIdx.z;
  const int dir = zi / Bn;
  const int b = zi - dir * Bn;
  const float* __restrict__ P = dir ? Bp : A;
  const float* __restrict__ Q = dir ? A : Bp;
  unsigned int* __restrict__ um = umin + ((size_t)dir * Bn + b) * N;

  const int t = threadIdx.x;
  const int ib0 = blockIdx.x * IB;
  const int jbase = blockIdx.y * jslice;
  const size_t boff = (size_t)b * 3 * N;
  const unsigned short one = 0x3F80u;  // bf16(1.0)

  // ---- stage A-vectors + |p|^2 (once) ----
  {
    int i = ib0 + t;
    float x = P[boff + i], y = P[boff + N + i], zz = P[boff + 2 * N + i];
    float ax = -2.f * x, ay = -2.f * y, az = -2.f * zz;
    unsigned short hx = f2bf(ax), hy = f2bf(ay), hz = f2bf(az);
    unsigned short lx = f2bf(ax - bf2f(hx)), ly = f2bf(ay - bf2f(hy)),
                   lz = f2bf(az - bf2f(hz));
    sA[0][t] = make_uint4(pk(hx, hy), pk(hz, lx), pk(ly, lz), pk(hx, hy));
    sA[1][t] = make_uint4(pk(hz, lx), pk(ly, lz), pk(one, one), pk(one, 0));
    sNP[t] = fmaf(zz, zz, fmaf(y, y, x * x));
  }
  __syncthreads();

  const int w = t >> 6, l = t & 63, m = l & 31, g = l >> 5;
  FragU a0u, a1u;
  a0u.u = sA[g][w * (MT * IA) + m];        // rows w*64 + 0..31
  a1u.u = sA[g][w * (MT * IA) + MT + m];   // rows w*64 + 32..63
  const short8 af0 = a0u.s, af1 = a1u.s;
  const uint4* __restrict__ sBg = sB[g];

  float run0[16], run1[16];
  f32x16 zc, dA, dB;
#pragma unroll
  for (int r = 0; r < 16; ++r) {
    run0[r] = 3.0e38f; run1[r] = 3.0e38f; zc[r] = 0.0f; dA[r] = 3.0e38f;
  }

  const int nch = jslice / TJQ;  // 8
  float qx = Q[boff + jbase + t];
  float qy = Q[boff + N + jbase + t];
  float qz = Q[boff + 2 * N + jbase + t];

  for (int ch = 0; ch < nch; ++ch) {
    unsigned short hx = f2bf(qx), hy = f2bf(qy), hz = f2bf(qz);
    unsigned short lx = f2bf(qx - bf2f(hx)), ly = f2bf(qy - bf2f(hy)),
                   lz = f2bf(qz - bf2f(hz));
    float nq = fmaf(qz, qz, fmaf(qy, qy, qx * qx));
    unsigned short nh = f2bf(nq);
    float r1 = nq - bf2f(nh);
    unsigned short nm = f2bf(r1);
    unsigned short nl = f2bf(r1 - bf2f(nm));
    uint4 b0s = make_uint4(pk(hx, hy), pk(hz, hx), pk(hy, hz), pk(lx, ly));
    uint4 b1s = make_uint4(pk(lz, lx), pk(ly, lz), pk(nh, nm), pk(nl, 0));

    {  // prefetch next chunk's q — stays IN FLIGHT across the raw barriers
      int jn = (ch + 1 < nch) ? (jbase + (ch + 1) * TJQ + t) : (jbase + t);
      qx = Q[boff + jn];
      qy = Q[boff + N + jn];
      qz = Q[boff + 2 * N + jn];
    }

    // R13: raw barriers — no compiler-forced s_waitcnt vmcnt(0) drain of the
    // q prefetch. Own ds_reads of the previous chunk are already consumed
    // (lgkm waits were inserted before their MFMAs), so barrier 1 is safe.
    asm volatile("" ::: "memory");
    __builtin_amdgcn_s_barrier();           // all waves done reading sB
    __builtin_amdgcn_sched_barrier(0);
    sB[0][t] = b0s;
    sB[1][t] = b1s;
    asm volatile("s_waitcnt lgkmcnt(0)" ::: "memory");  // own writes done
    __builtin_amdgcn_s_barrier();           // sB visible to all waves
    __builtin_amdgcn_sched_barrier(0);

    FragU cb0, cb1, nb0, nb1;
    cb0.u = sBg[m];
    cb1.u = sBg[MT + m];
#pragma unroll
    for (int p = 0; p < 8; ++p) {
      if (p < 7) {  // prefetch next pair's B-frags (consumed 8 steps later)
        nb0.u = sBg[(p + 1) * 64 + m];
        nb1.u = sBg[(p + 1) * 64 + MT + m];
      }
      // 2-deep pipeline; tile->run mapping lags by one MF:
      //   dA entering pair p holds (af1, b_{2p-1}) -> run1
      MF(dB, af0, cb0.s); SB0;   // T0 -> run0
      MIN16(run1, dA);    SB0;   // consume prev T3
      MF(dA, af0, cb1.s); SB0;   // T1 -> run0
      MIN16(run0, dB);    SB0;   // consume T0
      MF(dB, af1, cb0.s); SB0;   // T2 -> run1
      MIN16(run0, dA);    SB0;   // consume T1
      MF(dA, af1, cb1.s); SB0;   // T3 -> run1
      MIN16(run1, dB);    SB0;   // consume T2
      cb0 = nb0; cb1 = nb1;
    }
  }

  // drain the pipeline: dA holds the final (af1,b1) tile -> run1
  asm volatile("s_nop 7\n\ts_nop 7\n\ts_nop 1");
  __builtin_amdgcn_sched_barrier(0);
  MIN16(run1, dA);

  // ---- epilogue: min across 32 cols, add |p|^2, atomicMin ----
  // C/D layout (m74/m101): col=lane&31, row=(reg&3)+8*(reg>>2)+4*(lane>>5)
#pragma unroll
  for (int r = 0; r < 16; ++r) {
    float v0 = run0[r], v1 = run1[r];
#pragma unroll
    for (int sh = 1; sh <= 16; sh <<= 1) {
      v0 = fminf(v0, __shfl_xor(v0, sh));
      v1 = fminf(v1, __shfl_xor(v1, sh));
    }
    if (m == 0) {
      int row = (r & 3) + 8 * (r >> 2) + 4 * g;
      int il0 = w * (MT * IA) + row;
      int il1 = il0 + MT;
      atomicMin(&um[ib0 + il0], fmap(v0 + sNP[il0]));
      atomicMin(&um[ib0 + il1], fmap(v1 + sNP[il1]));
    }
  }
}

// Parallel final reduce: u holds complete squared distances (256 KB).
__global__ __launch_bounds__(256) void cl_reduce(
    const unsigned int* __restrict__ u, float* __restrict__ out, int total) {
  const int t = threadIdx.x;
  const uint4* __restrict__ u4 = (const uint4*)u;
  const int n4 = total / 4;
  const int gid = blockIdx.x * 256 + t;
  const int gstride = gridDim.x * 256;
  double s = 0.0;
  for (int i = gid; i < n4; i += gstride) {
    uint4 v = u4[i];
    s += (double)funmap(v.x) + (double)funmap(v.y) +
         (double)funmap(v.z) + (double)funmap(v.w);
  }
  for (int off = 32; off > 0; off >>= 1) s += __shfl_down(s, off, 64);
  __shared__ double sw[4];
  if ((t & 63) == 0) sw[t >> 6] = s;
  __syncthreads();
  if (t == 0) {
    double tot = sw[0] + sw[1] + sw[2] + sw[3];
    atomicAdd(out, (float)(tot / (double)total));
  }
}

extern "C" void kernel_launch(void* const* d_in, const int* in_sizes, int n_in,
                              void* d_out, int out_size, void* d_ws, size_t ws_size,
                              hipStream_t stream) {
  const float* in_pc = (const float*)d_in[0];
  const float* tgt_pc = (const float*)d_in[1];
  const int B = 2, N = 16384;
  unsigned int* u = (unsigned int*)d_ws;  // [2][B][N] uints = 256 KB
  float* out = (float*)d_out;

  hipMemsetAsync(u, 0xFF, (size_t)2 * B * N * sizeof(unsigned int), stream);
  hipMemsetAsync(out, 0, sizeof(float), stream);

  const int jslice = N / SJ;             // 4096
  dim3 grid(N / IB, SJ, 2 * B);          // (32,4,4) = 512 blocks x 512 thr
  cl_mfma<<<grid, dim3(BLK), 0, stream>>>(in_pc, tgt_pc, u, N, jslice, B);

  const int total = 2 * B * N;
  cl_reduce<<<dim3(16), dim3(256), 0, stream>>>(u, out, total);
}